// Round 7
// baseline (321.400 us; speedup 1.0000x reference)
//
#include <hip/hip_runtime.h>
#include <hip/hip_fp16.h>
#include <math.h>

#define N_NODES 50000
#define E_EDGES 1600000
#define NE_TOT  (E_EDGES + N_NODES)

// bucketed scatter geometry
#define BSH 7                                   // 128 nodes per bucket
#define NBKT ((N_NODES + 127) >> 7)             // 391 buckets
#define EPW 8192                                // edges per A-pass workgroup
#define NWA ((NE_TOT + EPW - 1) / EPW)          // 202 workgroups

#define CH 128                                  // staged edges per node chunk

// ---------------- bucketed CSR build ----------------

__global__ __launch_bounds__(256) void k_binhist(const int* __restrict__ ei,
                                                 int* __restrict__ histG) {
    __shared__ int h[NBKT];
    int t = threadIdx.x;
    for (int i = t; i < NBKT; i += 256) h[i] = 0;
    __syncthreads();
    int base = blockIdx.x * EPW;
    #pragma unroll 4
    for (int j = 0; j < EPW / 256; j++) {
        int e = base + t + 256 * j;
        if (e < NE_TOT) {
            int d = (e < E_EDGES) ? ei[E_EDGES + e] : (e - E_EDGES);
            atomicAdd(&h[d >> BSH], 1);
        }
    }
    __syncthreads();
    for (int i = t; i < NBKT; i += 256) histG[blockIdx.x * NBKT + i] = h[i];
}

__global__ void k_bktscan(int* __restrict__ histG, int* __restrict__ bktTotal) {
    int b = blockIdx.x * 256 + threadIdx.x;
    if (b >= NBKT) return;
    int run = 0;
    for (int w = 0; w < NWA; w++) {
        int v = histG[w * NBKT + b];
        histG[w * NBKT + b] = run;
        run += v;
    }
    bktTotal[b] = run;
}

__global__ __launch_bounds__(512) void k_bktbase(const int* __restrict__ bktTotal,
                                                 int* __restrict__ bktBase,
                                                 int* __restrict__ row_start) {
    __shared__ int sc[512];
    int t = threadIdx.x;
    int v = (t < NBKT) ? bktTotal[t] : 0;
    sc[t] = v;
    __syncthreads();
    for (int d = 1; d < 512; d <<= 1) {
        int x = (t >= d) ? sc[t - d] : 0;
        __syncthreads();
        sc[t] += x;
        __syncthreads();
    }
    if (t < NBKT) bktBase[t] = sc[t] - v;
    if (t == NBKT - 1) { bktBase[NBKT] = sc[t]; row_start[N_NODES] = sc[t]; }
}

__global__ __launch_bounds__(256) void k_binscatter(const int* __restrict__ ei,
                                                    const int* __restrict__ histG,
                                                    const int* __restrict__ bktBase,
                                                    int2* __restrict__ pairs) {
    __shared__ int lofs[NBKT];
    int t = threadIdx.x;
    for (int i = t; i < NBKT; i += 256)
        lofs[i] = bktBase[i] + histG[blockIdx.x * NBKT + i];
    __syncthreads();
    int base = blockIdx.x * EPW;
    #pragma unroll 4
    for (int j = 0; j < EPW / 256; j++) {
        int e = base + t + 256 * j;
        if (e < NE_TOT) {
            int s, d;
            if (e < E_EDGES) { s = ei[e]; d = ei[E_EDGES + e]; }
            else             { s = d = e - E_EDGES; }
            int pos = atomicAdd(&lofs[d >> BSH], 1);
            pairs[pos] = make_int2(s, d);
        }
    }
}

__global__ __launch_bounds__(256) void k_bucketsort(const int2* __restrict__ pairs,
                                                    const int* __restrict__ bktBase,
                                                    int* __restrict__ row_start,
                                                    int* __restrict__ col) {
    __shared__ int cnt[1 << BSH];
    __shared__ int sc[1 << BSH];
    __shared__ int cur[1 << BSH];
    int b = blockIdx.x, t = threadIdx.x;
    int nbeg = b << BSH;
    int ebeg = bktBase[b], eend = bktBase[b + 1];
    if (t < (1 << BSH)) cnt[t] = 0;
    __syncthreads();
    for (int j = ebeg + t; j < eend; j += 256)
        atomicAdd(&cnt[pairs[j].y - nbeg], 1);
    __syncthreads();
    int v = (t < (1 << BSH)) ? cnt[t] : 0;
    if (t < (1 << BSH)) sc[t] = v;
    __syncthreads();
    for (int d = 1; d < (1 << BSH); d <<= 1) {
        int x = 0;
        if (t < (1 << BSH) && t >= d) x = sc[t - d];
        __syncthreads();
        if (t < (1 << BSH)) sc[t] += x;
        __syncthreads();
    }
    if (t < (1 << BSH)) {
        int pos = ebeg + sc[t] - v;      // exclusive
        cur[t] = pos;
        int node = nbeg + t;
        if (node < N_NODES) row_start[node] = pos;
    }
    __syncthreads();
    for (int j = ebeg + t; j < eend; j += 256) {
        int2 p = pairs[j];
        int pos = atomicAdd(&cur[p.y - nbeg], 1);
        col[pos] = p.x;
    }
}

// ---------------- GEMM (128x128) + attention logits ----------------

__global__ __launch_bounds__(256) void k_gemm_att(
    const float* __restrict__ X, const float* __restrict__ W,
    const float* __restrict__ attS, const float* __restrict__ attD,
    __half* __restrict__ H16, float* __restrict__ a_s, float* __restrict__ a_d) {
    __shared__ float Wl[64 * 128];
    __shared__ float xs[32 * 64];
    int t = threadIdx.x;
    int g = t >> 5, cl = t & 31, c4 = cl * 4;
    int rowbase = blockIdx.x * 32;
    float4 acc[4];
    #pragma unroll
    for (int rr = 0; rr < 4; rr++) acc[rr] = make_float4(0.f, 0.f, 0.f, 0.f);

    for (int kp = 0; kp < 2; kp++) {
        __syncthreads();
        #pragma unroll
        for (int j = 0; j < 8; j++) {
            int f4 = t + 256 * j;
            int kk = f4 >> 5, cg = f4 & 31;
            *(float4*)&Wl[kk * 128 + cg * 4] =
                *(const float4*)&W[(kp * 64 + kk) * 128 + cg * 4];
        }
        #pragma unroll
        for (int j = 0; j < 2; j++) {
            int f4 = t + 256 * j;
            int r = f4 >> 4, k4 = f4 & 15;
            int grow = rowbase + r;
            float4 xv = make_float4(0.f, 0.f, 0.f, 0.f);
            if (grow < N_NODES) xv = *(const float4*)&X[grow * 128 + kp * 64 + k4 * 4];
            *(float4*)&xs[r * 64 + k4 * 4] = xv;
        }
        __syncthreads();
        #pragma unroll
        for (int k4 = 0; k4 < 16; k4++) {
            float4 xv[4];
            #pragma unroll
            for (int rr = 0; rr < 4; rr++)
                xv[rr] = *(float4*)&xs[(g * 4 + rr) * 64 + k4 * 4];
            #pragma unroll
            for (int kk = 0; kk < 4; kk++) {
                float4 wv = *(float4*)&Wl[(k4 * 4 + kk) * 128 + c4];
                #pragma unroll
                for (int rr = 0; rr < 4; rr++) {
                    float xc = (kk == 0) ? xv[rr].x : (kk == 1) ? xv[rr].y
                             : (kk == 2) ? xv[rr].z : xv[rr].w;
                    acc[rr].x += xc * wv.x;
                    acc[rr].y += xc * wv.y;
                    acc[rr].z += xc * wv.z;
                    acc[rr].w += xc * wv.w;
                }
            }
        }
    }

    float4 as4 = *(const float4*)&attS[c4];
    float4 ad4 = *(const float4*)&attD[c4];
    int head = cl >> 3;
    #pragma unroll
    for (int rr = 0; rr < 4; rr++) {
        int grow = rowbase + g * 4 + rr;
        float4 a = acc[rr];
        if (grow < N_NODES) {
            __half2 lo = __floats2half2_rn(a.x, a.y);
            __half2 hi = __floats2half2_rn(a.z, a.w);
            uint2 pk;
            pk.x = *(unsigned int*)&lo;
            pk.y = *(unsigned int*)&hi;
            *(uint2*)&H16[(size_t)grow * 128 + c4] = pk;
        }
        float ps = a.x * as4.x + a.y * as4.y + a.z * as4.z + a.w * as4.w;
        float pd = a.x * ad4.x + a.y * ad4.y + a.z * ad4.z + a.w * ad4.w;
        ps += __shfl_xor(ps, 1); ps += __shfl_xor(ps, 2); ps += __shfl_xor(ps, 4);
        pd += __shfl_xor(pd, 1); pd += __shfl_xor(pd, 2); pd += __shfl_xor(pd, 4);
        if ((cl & 7) == 0 && grow < N_NODES) {
            a_s[grow * 4 + head] = ps;
            a_d[grow * 4 + head] = pd;
        }
    }
}

// ---------------- Attention aggregation ----------------

__device__ inline float sel4(float4 v, int i) {
    float r = v.x;
    if (i == 1) r = v.y;
    if (i == 2) r = v.z;
    if (i == 3) r = v.w;
    return r;
}

__device__ inline float4 leaky4(float4 a, float4 b) {
    float4 e;
    e.x = a.x + b.x; e.x = e.x > 0.f ? e.x : 0.2f * e.x;
    e.y = a.y + b.y; e.y = e.y > 0.f ? e.y : 0.2f * e.y;
    e.z = a.z + b.z; e.z = e.z > 0.f ? e.z : 0.2f * e.z;
    e.w = a.w + b.w; e.w = e.w > 0.f ? e.w : 0.2f * e.w;
    return e;
}

// consume geometry: 8 edge slots x 8 channel-lanes x 16 ch/lane
template<int MODE>   // 1: layer-1 (ELU -> Hout fp32); 0: layer-2 (fused out-proj)
__global__ __launch_bounds__(256) void k_agg(
    const __half* __restrict__ H16, const float* __restrict__ a_s,
    const float* __restrict__ a_d, const int* __restrict__ row_start,
    const int* __restrict__ col, const float* __restrict__ bias,
    float* __restrict__ Hout,
    const float* __restrict__ Wout, const float* __restrict__ bout,
    float* __restrict__ out) {
    __shared__ float4 eS[4][CH];    // staged e -> p per wave
    __shared__ int    sS[4][CH];    // staged src byte-offset per wave
    __shared__ float  WoT[(MODE == 0) ? 8 * 136 : 1];  // transposed Wout, padded
    __shared__ float  boL[(MODE == 0) ? 8 : 1];

    if (MODE == 0) {
        for (int j = threadIdx.x; j < 1024; j += 256) {
            int o = j >> 7, k = j & 127;
            WoT[o * 136 + k] = Wout[k * 8 + o];
        }
        if (threadIdx.x < 8) boL[threadIdx.x] = bout[threadIdx.x];
        __syncthreads();
    }

    int wid = threadIdx.x >> 6;
    int lane = threadIdx.x & 63;
    int node = blockIdx.x * 4 + wid;
    if (node >= N_NODES) return;
    int beg = row_start[node], end = row_start[node + 1];
    int deg = end - beg;
    float4 ad4 = *(const float4*)&a_d[node * 4];
    float4* eA = eS[wid];
    int*    srcA = sS[wid];

    // pass 1: stage {src byte-offset, e4} for first CH edges, running max only
    float4 m = make_float4(-1e30f, -1e30f, -1e30f, -1e30f);
    for (int j = beg + lane; j < end; j += 64) {
        int src = col[j];
        float4 av = *(const float4*)&a_s[src * 4];
        float4 e = leaky4(av, ad4);
        int idx = j - beg;
        if (idx < CH) { srcA[idx] = src << 8; eA[idx] = e; }
        m.x = fmaxf(m.x, e.x); m.y = fmaxf(m.y, e.y);
        m.z = fmaxf(m.z, e.z); m.w = fmaxf(m.w, e.w);
    }
    #pragma unroll
    for (int off = 32; off > 0; off >>= 1) {
        m.x = fmaxf(m.x, __shfl_xor(m.x, off));
        m.y = fmaxf(m.y, __shfl_xor(m.y, off));
        m.z = fmaxf(m.z, __shfl_xor(m.z, off));
        m.w = fmaxf(m.w, __shfl_xor(m.w, off));
    }

    // convert staged e -> p = exp(e-m), accumulate partial denom
    float4 s = make_float4(0.f, 0.f, 0.f, 0.f);
    int nst = min(deg, CH);
    for (int idx = lane; idx < nst; idx += 64) {
        float4 e = eA[idx];
        float4 p;
        p.x = __expf(e.x - m.x); p.y = __expf(e.y - m.y);
        p.z = __expf(e.z - m.z); p.w = __expf(e.w - m.w);
        s.x += p.x; s.y += p.y; s.z += p.z; s.w += p.w;
        eA[idx] = p;
    }
    // tail edges beyond CH (rare): recompute for denom
    for (int j = beg + CH + lane; j < end; j += 64) {
        int src = col[j];
        float4 av = *(const float4*)&a_s[src * 4];
        float4 e = leaky4(av, ad4);
        s.x += __expf(e.x - m.x); s.y += __expf(e.y - m.y);
        s.z += __expf(e.z - m.z); s.w += __expf(e.w - m.w);
    }
    #pragma unroll
    for (int off = 32; off > 0; off >>= 1) {
        s.x += __shfl_xor(s.x, off);
        s.y += __shfl_xor(s.y, off);
        s.z += __shfl_xor(s.z, off);
        s.w += __shfl_xor(s.w, off);
    }
    float4 inv;
    inv.x = 1.f / (s.x + 1e-16f);
    inv.y = 1.f / (s.y + 1e-16f);
    inv.z = 1.f / (s.z + 1e-16f);
    inv.w = 1.f / (s.w + 1e-16f);

    // consume: 8 edge slots x 8 ch-lanes (16 fp16 ch each = 2x16B loads)
    int eslot = lane >> 3, cl8 = lane & 7, head = cl8 >> 1;
    const char* hbyte = (const char*)H16 + cl8 * 32;
    const float* pA = (const float*)eA;
    float acc[16];
    #pragma unroll
    for (int k = 0; k < 16; k++) acc[k] = 0.f;

    #pragma unroll 2
    for (int i = eslot; i < nst; i += 8) {
        int off = srcA[i];
        float p = pA[i * 4 + head];
        float4 r0 = *(const float4*)(hbyte + off);
        float4 r1 = *(const float4*)(hbyte + off + 16);
        const __half* h0 = (const __half*)&r0;
        const __half* h1 = (const __half*)&r1;
        #pragma unroll
        for (int k = 0; k < 8; k++) acc[k]     = fmaf(p, __half2float(h0[k]), acc[k]);
        #pragma unroll
        for (int k = 0; k < 8; k++) acc[8 + k] = fmaf(p, __half2float(h1[k]), acc[8 + k]);
    }
    // overflow chunks (deg > CH, rare): restage then consume
    for (int cb = beg + CH; cb < end; cb += CH) {
        int cnt = min(end - cb, CH);
        for (int idx = lane; idx < cnt; idx += 64) {
            int src = col[cb + idx];
            float4 av = *(const float4*)&a_s[src * 4];
            float4 e = leaky4(av, ad4);
            float4 p;
            p.x = __expf(e.x - m.x); p.y = __expf(e.y - m.y);
            p.z = __expf(e.z - m.z); p.w = __expf(e.w - m.w);
            srcA[idx] = src << 8; eA[idx] = p;
        }
        #pragma unroll 2
        for (int i = eslot; i < cnt; i += 8) {
            int off = srcA[i];
            float p = pA[i * 4 + head];
            float4 r0 = *(const float4*)(hbyte + off);
            float4 r1 = *(const float4*)(hbyte + off + 16);
            const __half* h0 = (const __half*)&r0;
            const __half* h1 = (const __half*)&r1;
            #pragma unroll
            for (int k = 0; k < 8; k++) acc[k]     = fmaf(p, __half2float(h0[k]), acc[k]);
            #pragma unroll
            for (int k = 0; k < 8; k++) acc[8 + k] = fmaf(p, __half2float(h1[k]), acc[8 + k]);
        }
    }

    // reduce over the 8 edge slots (lane bits 3,4,5)
    #pragma unroll
    for (int k = 0; k < 16; k++) {
        acc[k] += __shfl_xor(acc[k], 8);
        acc[k] += __shfl_xor(acc[k], 16);
        acc[k] += __shfl_xor(acc[k], 32);
    }

    float ih = sel4(inv, head);
    if (MODE == 1) {
        if (eslot == 0) {
            const float* bp = &bias[cl8 * 16];
            float o[16];
            #pragma unroll
            for (int k = 0; k < 16; k++) {
                o[k] = acc[k] * ih + bp[k];
                o[k] = o[k] > 0.f ? o[k] : expm1f(o[k]);
            }
            float* op = &Hout[(size_t)node * 128 + cl8 * 16];
            #pragma unroll
            for (int q = 0; q < 4; q++)
                *(float4*)&op[q * 4] = make_float4(o[q*4], o[q*4+1], o[q*4+2], o[q*4+3]);
        }
    } else {
        // fused output projection: every lane holds reduced acc for its 16 ch;
        // slot s computes output s
        const float* bp = &bias[cl8 * 16];
        float h2[16];
        #pragma unroll
        for (int k = 0; k < 16; k++) h2[k] = acc[k] * ih + bp[k];
        const float* wr = &WoT[eslot * 136 + cl8 * 16];
        float pp = 0.f;
        #pragma unroll
        for (int k = 0; k < 16; k++) pp = fmaf(h2[k], wr[k], pp);
        pp += __shfl_xor(pp, 1);
        pp += __shfl_xor(pp, 2);
        pp += __shfl_xor(pp, 4);
        if (cl8 == 0) out[(size_t)node * 8 + eslot] = pp + boL[eslot];
    }
}

// ---------------- launch ----------------

extern "C" void kernel_launch(void* const* d_in, const int* in_sizes, int n_in,
                              void* d_out, int out_size, void* d_ws, size_t ws_size,
                              hipStream_t stream) {
    const float* x     = (const float*)d_in[0];
    const int*   ei    = (const int*)d_in[1];
    const float* W1    = (const float*)d_in[2];
    const float* attS1 = (const float*)d_in[3];
    const float* attD1 = (const float*)d_in[4];
    const float* b1    = (const float*)d_in[5];
    const float* W2    = (const float*)d_in[6];
    const float* attS2 = (const float*)d_in[7];
    const float* attD2 = (const float*)d_in[8];
    const float* b2    = (const float*)d_in[9];
    const float* Wout  = (const float*)d_in[10];
    const float* bout  = (const float*)d_in[11];
    float* out = (float*)d_out;

    char* ws = (char*)d_ws;
    size_t off = 0;
    auto alloc = [&](size_t bytes) -> void* {
        void* p = ws + off;
        off += (bytes + 255) & ~(size_t)255;
        return p;
    };
    float*  hB        = (float*)alloc((size_t)N_NODES * 128 * 4);
    __half* h16       = (__half*)alloc((size_t)N_NODES * 128 * 2);
    float*  a_s       = (float*)alloc((size_t)N_NODES * 4 * 4);
    float*  a_d       = (float*)alloc((size_t)N_NODES * 4 * 4);
    int*    row_start = (int*)alloc((size_t)(N_NODES + 1) * 4);
    int*    col       = (int*)alloc((size_t)NE_TOT * 4);
    int*    histG     = (int*)alloc((size_t)NWA * NBKT * 4);
    int*    bktTotal  = (int*)alloc((size_t)NBKT * 4);
    int*    bktBase   = (int*)alloc((size_t)(NBKT + 1) * 4);
    int2*   pairs     = (int2*)hB;   // alias: hB not live during CSR build

    k_binhist<<<NWA, 256, 0, stream>>>(ei, histG);
    k_bktscan<<<(NBKT + 255) / 256, 256, 0, stream>>>(histG, bktTotal);
    k_bktbase<<<1, 512, 0, stream>>>(bktTotal, bktBase, row_start);
    k_binscatter<<<NWA, 256, 0, stream>>>(ei, histG, bktBase, pairs);
    k_bucketsort<<<NBKT, 256, 0, stream>>>(pairs, bktBase, row_start, col);

    int nbG = (N_NODES + 31) / 32;
    int nbA = (N_NODES + 3) / 4;
    k_gemm_att<<<nbG, 256, 0, stream>>>(x, W1, attS1, attD1, h16, a_s, a_d);
    k_agg<1><<<nbA, 256, 0, stream>>>(h16, a_s, a_d, row_start, col, b1, hB,
                                      Wout, bout, out);
    k_gemm_att<<<nbG, 256, 0, stream>>>(hB, W2, attS2, attD2, h16, a_s, a_d);
    k_agg<0><<<nbA, 256, 0, stream>>>(h16, a_s, a_d, row_start, col, b2, hB,
                                      Wout, bout, out);
}

// Round 8
// 271.546 us; speedup vs baseline: 1.1836x; 1.1836x over previous
//
#include <hip/hip_runtime.h>
#include <hip/hip_fp16.h>
#include <math.h>

#define N_NODES 50000
#define E_EDGES 1600000
#define NE_TOT  (E_EDGES + N_NODES)

// bucketed scatter geometry
#define BSH 7                                   // 128 nodes per bucket
#define NBKT ((N_NODES + 127) >> 7)             // 391 buckets
#define EPW 4096                                // edges per A-pass workgroup
#define NWA ((NE_TOT + EPW - 1) / EPW)          // 403 workgroups

#define CH 128                                  // staged edges per node chunk

// ---------------- bucketed CSR build ----------------

__global__ __launch_bounds__(256) void k_binhist(const int* __restrict__ ei,
                                                 int* __restrict__ histG) {
    __shared__ int h[NBKT];
    int t = threadIdx.x;
    for (int i = t; i < NBKT; i += 256) h[i] = 0;
    __syncthreads();
    int base = blockIdx.x * EPW;
    #pragma unroll 4
    for (int j = 0; j < EPW / 256; j++) {
        int e = base + t + 256 * j;
        if (e < NE_TOT) {
            int d = (e < E_EDGES) ? ei[E_EDGES + e] : (e - E_EDGES);
            atomicAdd(&h[d >> BSH], 1);
        }
    }
    __syncthreads();
    for (int i = t; i < NBKT; i += 256) histG[blockIdx.x * NBKT + i] = h[i];
}

// block-per-bucket parallel scan over the workgroup axis
__global__ __launch_bounds__(512) void k_bktscan(int* __restrict__ histG,
                                                 int* __restrict__ bktTotal) {
    __shared__ int sh[512];
    int b = blockIdx.x;            // bucket
    int t = threadIdx.x;           // workgroup index
    int v = (t < NWA) ? histG[t * NBKT + b] : 0;
    sh[t] = v;
    __syncthreads();
    for (int d = 1; d < 512; d <<= 1) {
        int x = (t >= d) ? sh[t - d] : 0;
        __syncthreads();
        sh[t] += x;
        __syncthreads();
    }
    if (t < NWA) histG[t * NBKT + b] = sh[t] - v;   // exclusive
    if (t == 511) bktTotal[b] = sh[511];
}

__global__ __launch_bounds__(512) void k_bktbase(const int* __restrict__ bktTotal,
                                                 int* __restrict__ bktBase,
                                                 int* __restrict__ row_start) {
    __shared__ int sc[512];
    int t = threadIdx.x;
    int v = (t < NBKT) ? bktTotal[t] : 0;
    sc[t] = v;
    __syncthreads();
    for (int d = 1; d < 512; d <<= 1) {
        int x = (t >= d) ? sc[t - d] : 0;
        __syncthreads();
        sc[t] += x;
        __syncthreads();
    }
    if (t < NBKT) bktBase[t] = sc[t] - v;
    if (t == NBKT - 1) { bktBase[NBKT] = sc[t]; row_start[N_NODES] = sc[t]; }
}

__global__ __launch_bounds__(256) void k_binscatter(const int* __restrict__ ei,
                                                    const int* __restrict__ histG,
                                                    const int* __restrict__ bktBase,
                                                    int2* __restrict__ pairs) {
    __shared__ int lofs[NBKT];
    int t = threadIdx.x;
    for (int i = t; i < NBKT; i += 256)
        lofs[i] = bktBase[i] + histG[blockIdx.x * NBKT + i];
    __syncthreads();
    int base = blockIdx.x * EPW;
    #pragma unroll 4
    for (int j = 0; j < EPW / 256; j++) {
        int e = base + t + 256 * j;
        if (e < NE_TOT) {
            int s, d;
            if (e < E_EDGES) { s = ei[e]; d = ei[E_EDGES + e]; }
            else             { s = d = e - E_EDGES; }
            int pos = atomicAdd(&lofs[d >> BSH], 1);
            pairs[pos] = make_int2(s, d);
        }
    }
}

__global__ __launch_bounds__(256) void k_bucketsort(const int2* __restrict__ pairs,
                                                    const int* __restrict__ bktBase,
                                                    int* __restrict__ row_start,
                                                    int* __restrict__ col) {
    __shared__ int cnt[1 << BSH];
    __shared__ int sc[1 << BSH];
    __shared__ int cur[1 << BSH];
    int b = blockIdx.x, t = threadIdx.x;
    int nbeg = b << BSH;
    int ebeg = bktBase[b], eend = bktBase[b + 1];
    if (t < (1 << BSH)) cnt[t] = 0;
    __syncthreads();
    for (int j = ebeg + t; j < eend; j += 256)
        atomicAdd(&cnt[pairs[j].y - nbeg], 1);
    __syncthreads();
    int v = (t < (1 << BSH)) ? cnt[t] : 0;
    if (t < (1 << BSH)) sc[t] = v;
    __syncthreads();
    for (int d = 1; d < (1 << BSH); d <<= 1) {
        int x = 0;
        if (t < (1 << BSH) && t >= d) x = sc[t - d];
        __syncthreads();
        if (t < (1 << BSH)) sc[t] += x;
        __syncthreads();
    }
    if (t < (1 << BSH)) {
        int pos = ebeg + sc[t] - v;      // exclusive
        cur[t] = pos;
        int node = nbeg + t;
        if (node < N_NODES) row_start[node] = pos;
    }
    __syncthreads();
    for (int j = ebeg + t; j < eend; j += 256) {
        int2 p = pairs[j];
        int pos = atomicAdd(&cur[p.y - nbeg], 1);
        col[pos] = p.x;
    }
}

// ---------------- GEMM (128x128) + attention logits ----------------

__global__ __launch_bounds__(256) void k_gemm_att(
    const float* __restrict__ X, const float* __restrict__ W,
    const float* __restrict__ attS, const float* __restrict__ attD,
    __half* __restrict__ H16, float* __restrict__ a_s, float* __restrict__ a_d) {
    __shared__ float Wl[64 * 128];
    __shared__ float xs[32 * 64];
    int t = threadIdx.x;
    int g = t >> 5, cl = t & 31, c4 = cl * 4;
    int rowbase = blockIdx.x * 32;
    float4 acc[4];
    #pragma unroll
    for (int rr = 0; rr < 4; rr++) acc[rr] = make_float4(0.f, 0.f, 0.f, 0.f);

    for (int kp = 0; kp < 2; kp++) {
        __syncthreads();
        #pragma unroll
        for (int j = 0; j < 8; j++) {
            int f4 = t + 256 * j;
            int kk = f4 >> 5, cg = f4 & 31;
            *(float4*)&Wl[kk * 128 + cg * 4] =
                *(const float4*)&W[(kp * 64 + kk) * 128 + cg * 4];
        }
        #pragma unroll
        for (int j = 0; j < 2; j++) {
            int f4 = t + 256 * j;
            int r = f4 >> 4, k4 = f4 & 15;
            int grow = rowbase + r;
            float4 xv = make_float4(0.f, 0.f, 0.f, 0.f);
            if (grow < N_NODES) xv = *(const float4*)&X[grow * 128 + kp * 64 + k4 * 4];
            *(float4*)&xs[r * 64 + k4 * 4] = xv;
        }
        __syncthreads();
        #pragma unroll
        for (int k4 = 0; k4 < 16; k4++) {
            float4 xv[4];
            #pragma unroll
            for (int rr = 0; rr < 4; rr++)
                xv[rr] = *(float4*)&xs[(g * 4 + rr) * 64 + k4 * 4];
            #pragma unroll
            for (int kk = 0; kk < 4; kk++) {
                float4 wv = *(float4*)&Wl[(k4 * 4 + kk) * 128 + c4];
                #pragma unroll
                for (int rr = 0; rr < 4; rr++) {
                    float xc = (kk == 0) ? xv[rr].x : (kk == 1) ? xv[rr].y
                             : (kk == 2) ? xv[rr].z : xv[rr].w;
                    acc[rr].x += xc * wv.x;
                    acc[rr].y += xc * wv.y;
                    acc[rr].z += xc * wv.z;
                    acc[rr].w += xc * wv.w;
                }
            }
        }
    }

    float4 as4 = *(const float4*)&attS[c4];
    float4 ad4 = *(const float4*)&attD[c4];
    int head = cl >> 3;
    #pragma unroll
    for (int rr = 0; rr < 4; rr++) {
        int grow = rowbase + g * 4 + rr;
        float4 a = acc[rr];
        if (grow < N_NODES) {
            __half2 lo = __floats2half2_rn(a.x, a.y);
            __half2 hi = __floats2half2_rn(a.z, a.w);
            uint2 pk;
            pk.x = *(unsigned int*)&lo;
            pk.y = *(unsigned int*)&hi;
            *(uint2*)&H16[(size_t)grow * 128 + c4] = pk;
        }
        float ps = a.x * as4.x + a.y * as4.y + a.z * as4.z + a.w * as4.w;
        float pd = a.x * ad4.x + a.y * ad4.y + a.z * ad4.z + a.w * ad4.w;
        ps += __shfl_xor(ps, 1); ps += __shfl_xor(ps, 2); ps += __shfl_xor(ps, 4);
        pd += __shfl_xor(pd, 1); pd += __shfl_xor(pd, 2); pd += __shfl_xor(pd, 4);
        if ((cl & 7) == 0 && grow < N_NODES) {
            a_s[grow * 4 + head] = ps;
            a_d[grow * 4 + head] = pd;
        }
    }
}

// ---------------- Attention aggregation ----------------

__device__ inline float sel4(float4 v, int i) {
    float r = v.x;
    if (i == 1) r = v.y;
    if (i == 2) r = v.z;
    if (i == 3) r = v.w;
    return r;
}

__device__ inline float4 leaky4(float4 a, float4 b) {
    float4 e;
    e.x = a.x + b.x; e.x = e.x > 0.f ? e.x : 0.2f * e.x;
    e.y = a.y + b.y; e.y = e.y > 0.f ? e.y : 0.2f * e.y;
    e.z = a.z + b.z; e.z = e.z > 0.f ? e.z : 0.2f * e.z;
    e.w = a.w + b.w; e.w = e.w > 0.f ? e.w : 0.2f * e.w;
    return e;
}

// consume geometry: 4 edge slots x 16 channel-lanes x 8 ch/lane (R6 layout)
template<int MODE>   // 1: layer-1 (ELU -> Hout fp32); 0: layer-2 (fused out-proj)
__global__ __launch_bounds__(256) void k_agg(
    const __half* __restrict__ H16, const float* __restrict__ a_s,
    const float* __restrict__ a_d, const int* __restrict__ row_start,
    const int* __restrict__ col, const float* __restrict__ bias,
    float* __restrict__ Hout,
    const float* __restrict__ Wout, const float* __restrict__ bout,
    float* __restrict__ out) {
    __shared__ float4 eS[4][CH];    // staged e -> p per wave
    __shared__ int    sS[4][CH];    // staged src per wave
    __shared__ float  WoT[(MODE == 0) ? 1024 : 1];  // transposed Wout [8][128]
    __shared__ float  boL[(MODE == 0) ? 8 : 1];

    if (MODE == 0) {
        for (int j = threadIdx.x; j < 1024; j += 256) {
            int o = j >> 7, k = j & 127;
            WoT[o * 128 + k] = Wout[k * 8 + o];
        }
        if (threadIdx.x < 8) boL[threadIdx.x] = bout[threadIdx.x];
        __syncthreads();
    }

    int wid = threadIdx.x >> 6;
    int lane = threadIdx.x & 63;
    int node = blockIdx.x * 4 + wid;
    if (node >= N_NODES) return;
    int beg = row_start[node], end = row_start[node + 1];
    int deg = end - beg;
    float4 ad4 = *(const float4*)&a_d[node * 4];
    float4* eA = eS[wid];
    int*    srcA = sS[wid];

    // pass 1: stage {src, e4} for first CH edges, track running max only
    float4 m = make_float4(-1e30f, -1e30f, -1e30f, -1e30f);
    for (int j = beg + lane; j < end; j += 64) {
        int src = col[j];
        float4 av = *(const float4*)&a_s[src * 4];
        float4 e = leaky4(av, ad4);
        int idx = j - beg;
        if (idx < CH) { srcA[idx] = src; eA[idx] = e; }
        m.x = fmaxf(m.x, e.x); m.y = fmaxf(m.y, e.y);
        m.z = fmaxf(m.z, e.z); m.w = fmaxf(m.w, e.w);
    }
    #pragma unroll
    for (int off = 32; off > 0; off >>= 1) {
        m.x = fmaxf(m.x, __shfl_xor(m.x, off));
        m.y = fmaxf(m.y, __shfl_xor(m.y, off));
        m.z = fmaxf(m.z, __shfl_xor(m.z, off));
        m.w = fmaxf(m.w, __shfl_xor(m.w, off));
    }

    // convert staged e -> p = exp(e-m), accumulate partial denom
    float4 s = make_float4(0.f, 0.f, 0.f, 0.f);
    int nst = min(deg, CH);
    for (int idx = lane; idx < nst; idx += 64) {
        float4 e = eA[idx];
        float4 p;
        p.x = __expf(e.x - m.x); p.y = __expf(e.y - m.y);
        p.z = __expf(e.z - m.z); p.w = __expf(e.w - m.w);
        s.x += p.x; s.y += p.y; s.z += p.z; s.w += p.w;
        eA[idx] = p;
    }
    // tail edges beyond CH (rare): recompute for denom
    for (int j = beg + CH + lane; j < end; j += 64) {
        int src = col[j];
        float4 av = *(const float4*)&a_s[src * 4];
        float4 e = leaky4(av, ad4);
        s.x += __expf(e.x - m.x); s.y += __expf(e.y - m.y);
        s.z += __expf(e.z - m.z); s.w += __expf(e.w - m.w);
    }
    #pragma unroll
    for (int off = 32; off > 0; off >>= 1) {
        s.x += __shfl_xor(s.x, off);
        s.y += __shfl_xor(s.y, off);
        s.z += __shfl_xor(s.z, off);
        s.w += __shfl_xor(s.w, off);
    }
    float4 inv;
    inv.x = 1.f / (s.x + 1e-16f);
    inv.y = 1.f / (s.y + 1e-16f);
    inv.z = 1.f / (s.z + 1e-16f);
    inv.w = 1.f / (s.w + 1e-16f);

    // consume: 4 edge slots x 16 channel-lanes (8 fp16 ch each = 16B load)
    int eslot = lane >> 4, cl16 = lane & 15, head = cl16 >> 2;
    const __half* hbase = H16 + cl16 * 8;
    const float* pA = (const float*)eA;
    float acc8[8];
    #pragma unroll
    for (int k = 0; k < 8; k++) acc8[k] = 0.f;

    #pragma unroll 4
    for (int i = eslot; i < nst; i += 4) {
        int src = srcA[i];
        float p = pA[i * 4 + head];
        float4 raw = *(const float4*)(hbase + (size_t)src * 128);
        const __half2* hp = (const __half2*)&raw;
        float2 f0 = __half22float2(hp[0]);
        float2 f1 = __half22float2(hp[1]);
        float2 f2 = __half22float2(hp[2]);
        float2 f3 = __half22float2(hp[3]);
        acc8[0] = fmaf(p, f0.x, acc8[0]); acc8[1] = fmaf(p, f0.y, acc8[1]);
        acc8[2] = fmaf(p, f1.x, acc8[2]); acc8[3] = fmaf(p, f1.y, acc8[3]);
        acc8[4] = fmaf(p, f2.x, acc8[4]); acc8[5] = fmaf(p, f2.y, acc8[5]);
        acc8[6] = fmaf(p, f3.x, acc8[6]); acc8[7] = fmaf(p, f3.y, acc8[7]);
    }
    // overflow chunks (deg > CH, rare): restage then consume
    for (int cb = beg + CH; cb < end; cb += CH) {
        int cnt = min(end - cb, CH);
        for (int idx = lane; idx < cnt; idx += 64) {
            int src = col[cb + idx];
            float4 av = *(const float4*)&a_s[src * 4];
            float4 e = leaky4(av, ad4);
            float4 p;
            p.x = __expf(e.x - m.x); p.y = __expf(e.y - m.y);
            p.z = __expf(e.z - m.z); p.w = __expf(e.w - m.w);
            srcA[idx] = src; eA[idx] = p;
        }
        #pragma unroll 4
        for (int i = eslot; i < cnt; i += 4) {
            int src = srcA[i];
            float p = pA[i * 4 + head];
            float4 raw = *(const float4*)(hbase + (size_t)src * 128);
            const __half2* hp = (const __half2*)&raw;
            float2 f0 = __half22float2(hp[0]);
            float2 f1 = __half22float2(hp[1]);
            float2 f2 = __half22float2(hp[2]);
            float2 f3 = __half22float2(hp[3]);
            acc8[0] = fmaf(p, f0.x, acc8[0]); acc8[1] = fmaf(p, f0.y, acc8[1]);
            acc8[2] = fmaf(p, f1.x, acc8[2]); acc8[3] = fmaf(p, f1.y, acc8[3]);
            acc8[4] = fmaf(p, f2.x, acc8[4]); acc8[5] = fmaf(p, f2.y, acc8[5]);
            acc8[6] = fmaf(p, f3.x, acc8[6]); acc8[7] = fmaf(p, f3.y, acc8[7]);
        }
    }

    #pragma unroll
    for (int k = 0; k < 8; k++) {
        acc8[k] += __shfl_xor(acc8[k], 16);
        acc8[k] += __shfl_xor(acc8[k], 32);
    }

    float ih = sel4(inv, head);
    if (MODE == 1) {
        if (eslot == 0) {
            const float* bp = &bias[cl16 * 8];
            float o[8];
            #pragma unroll
            for (int k = 0; k < 8; k++) {
                o[k] = acc8[k] * ih + bp[k];
                o[k] = o[k] > 0.f ? o[k] : expm1f(o[k]);
            }
            float* op = &Hout[(size_t)node * 128 + cl16 * 8];
            *(float4*)&op[0] = make_float4(o[0], o[1], o[2], o[3]);
            *(float4*)&op[4] = make_float4(o[4], o[5], o[6], o[7]);
        }
    } else {
        // fused output projection: h2 = acc*ih + b2 (all lanes hold it),
        // each eslot computes 2 of the 8 outputs
        const float* bp = &bias[cl16 * 8];
        float4 oa, ob;
        oa.x = acc8[0] * ih + bp[0]; oa.y = acc8[1] * ih + bp[1];
        oa.z = acc8[2] * ih + bp[2]; oa.w = acc8[3] * ih + bp[3];
        ob.x = acc8[4] * ih + bp[4]; ob.y = acc8[5] * ih + bp[5];
        ob.z = acc8[6] * ih + bp[6]; ob.w = acc8[7] * ih + bp[7];
        int o0 = eslot * 2;
        float p0 = 0.f, p1 = 0.f;
        {
            float4 wa = *(float4*)&WoT[o0 * 128 + cl16 * 8];
            float4 wb = *(float4*)&WoT[o0 * 128 + cl16 * 8 + 4];
            p0 = oa.x * wa.x + oa.y * wa.y + oa.z * wa.z + oa.w * wa.w
               + ob.x * wb.x + ob.y * wb.y + ob.z * wb.z + ob.w * wb.w;
            float4 wc = *(float4*)&WoT[(o0 + 1) * 128 + cl16 * 8];
            float4 wd = *(float4*)&WoT[(o0 + 1) * 128 + cl16 * 8 + 4];
            p1 = oa.x * wc.x + oa.y * wc.y + oa.z * wc.z + oa.w * wc.w
               + ob.x * wd.x + ob.y * wd.y + ob.z * wd.z + ob.w * wd.w;
        }
        #pragma unroll
        for (int d = 1; d <= 8; d <<= 1) {
            p0 += __shfl_xor(p0, d);
            p1 += __shfl_xor(p1, d);
        }
        if (cl16 == 0) {
            float2 ov = make_float2(p0 + boL[o0], p1 + boL[o0 + 1]);
            *(float2*)&out[(size_t)node * 8 + o0] = ov;
        }
    }
}

// ---------------- launch ----------------

extern "C" void kernel_launch(void* const* d_in, const int* in_sizes, int n_in,
                              void* d_out, int out_size, void* d_ws, size_t ws_size,
                              hipStream_t stream) {
    const float* x     = (const float*)d_in[0];
    const int*   ei    = (const int*)d_in[1];
    const float* W1    = (const float*)d_in[2];
    const float* attS1 = (const float*)d_in[3];
    const float* attD1 = (const float*)d_in[4];
    const float* b1    = (const float*)d_in[5];
    const float* W2    = (const float*)d_in[6];
    const float* attS2 = (const float*)d_in[7];
    const float* attD2 = (const float*)d_in[8];
    const float* b2    = (const float*)d_in[9];
    const float* Wout  = (const float*)d_in[10];
    const float* bout  = (const float*)d_in[11];
    float* out = (float*)d_out;

    char* ws = (char*)d_ws;
    size_t off = 0;
    auto alloc = [&](size_t bytes) -> void* {
        void* p = ws + off;
        off += (bytes + 255) & ~(size_t)255;
        return p;
    };
    float*  hB        = (float*)alloc((size_t)N_NODES * 128 * 4);
    __half* h16       = (__half*)alloc((size_t)N_NODES * 128 * 2);
    float*  a_s       = (float*)alloc((size_t)N_NODES * 4 * 4);
    float*  a_d       = (float*)alloc((size_t)N_NODES * 4 * 4);
    int*    row_start = (int*)alloc((size_t)(N_NODES + 1) * 4);
    int*    col       = (int*)alloc((size_t)NE_TOT * 4);
    int*    histG     = (int*)alloc((size_t)NWA * NBKT * 4);
    int*    bktTotal  = (int*)alloc((size_t)NBKT * 4);
    int*    bktBase   = (int*)alloc((size_t)(NBKT + 1) * 4);
    int2*   pairs     = (int2*)hB;   // alias: hB not live during CSR build

    k_binhist<<<NWA, 256, 0, stream>>>(ei, histG);
    k_bktscan<<<NBKT, 512, 0, stream>>>(histG, bktTotal);
    k_bktbase<<<1, 512, 0, stream>>>(bktTotal, bktBase, row_start);
    k_binscatter<<<NWA, 256, 0, stream>>>(ei, histG, bktBase, pairs);
    k_bucketsort<<<NBKT, 256, 0, stream>>>(pairs, bktBase, row_start, col);

    int nbG = (N_NODES + 31) / 32;
    int nbA = (N_NODES + 3) / 4;
    k_gemm_att<<<nbG, 256, 0, stream>>>(x, W1, attS1, attD1, h16, a_s, a_d);
    k_agg<1><<<nbA, 256, 0, stream>>>(h16, a_s, a_d, row_start, col, b1, hB,
                                      Wout, bout, out);
    k_gemm_att<<<nbG, 256, 0, stream>>>(hB, W2, attS2, attD2, h16, a_s, a_d);
    k_agg<0><<<nbA, 256, 0, stream>>>(h16, a_s, a_d, row_start, col, b2, hB,
                                      Wout, bout, out);
}

// Round 9
// 268.509 us; speedup vs baseline: 1.1970x; 1.0113x over previous
//
#include <hip/hip_runtime.h>
#include <hip/hip_fp16.h>
#include <math.h>

#define N_NODES 50000
#define E_EDGES 1600000
#define NE_TOT  (E_EDGES + N_NODES)

// bucketed scatter geometry
#define BSH 7                                   // 128 nodes per bucket
#define NBKT ((N_NODES + 127) >> 7)             // 391 buckets
#define EPW 4096                                // edges per A-pass workgroup
#define NWA ((NE_TOT + EPW - 1) / EPW)          // 403 workgroups

#define CH 128                                  // staged edges per node chunk

// ---------------- fused: per-WG bucket histogram  ||  layer-1 GEMM ----------------
// blocks [0, NWA): binhist; blocks [NWA, NWA+nbG): GEMM+att-logits.
// Branch is block-uniform; LDS is a union (GEMM needs 40KB, hist 1.6KB).

__device__ __forceinline__ void gemm_att_body(
    int bid, int t, float* Wl, float* xs,
    const float* __restrict__ X, const float* __restrict__ W,
    const float* __restrict__ attS, const float* __restrict__ attD,
    __half* __restrict__ H16, float* __restrict__ a_s, float* __restrict__ a_d) {
    int g = t >> 5, cl = t & 31, c4 = cl * 4;
    int rowbase = bid * 32;
    float4 acc[4];
    #pragma unroll
    for (int rr = 0; rr < 4; rr++) acc[rr] = make_float4(0.f, 0.f, 0.f, 0.f);

    for (int kp = 0; kp < 2; kp++) {
        __syncthreads();
        #pragma unroll
        for (int j = 0; j < 8; j++) {
            int f4 = t + 256 * j;
            int kk = f4 >> 5, cg = f4 & 31;
            *(float4*)&Wl[kk * 128 + cg * 4] =
                *(const float4*)&W[(kp * 64 + kk) * 128 + cg * 4];
        }
        #pragma unroll
        for (int j = 0; j < 2; j++) {
            int f4 = t + 256 * j;
            int r = f4 >> 4, k4 = f4 & 15;
            int grow = rowbase + r;
            float4 xv = make_float4(0.f, 0.f, 0.f, 0.f);
            if (grow < N_NODES) xv = *(const float4*)&X[grow * 128 + kp * 64 + k4 * 4];
            *(float4*)&xs[r * 64 + k4 * 4] = xv;
        }
        __syncthreads();
        #pragma unroll
        for (int k4 = 0; k4 < 16; k4++) {
            float4 xv[4];
            #pragma unroll
            for (int rr = 0; rr < 4; rr++)
                xv[rr] = *(float4*)&xs[(g * 4 + rr) * 64 + k4 * 4];
            #pragma unroll
            for (int kk = 0; kk < 4; kk++) {
                float4 wv = *(float4*)&Wl[(k4 * 4 + kk) * 128 + c4];
                #pragma unroll
                for (int rr = 0; rr < 4; rr++) {
                    float xc = (kk == 0) ? xv[rr].x : (kk == 1) ? xv[rr].y
                             : (kk == 2) ? xv[rr].z : xv[rr].w;
                    acc[rr].x += xc * wv.x;
                    acc[rr].y += xc * wv.y;
                    acc[rr].z += xc * wv.z;
                    acc[rr].w += xc * wv.w;
                }
            }
        }
    }

    float4 as4 = *(const float4*)&attS[c4];
    float4 ad4 = *(const float4*)&attD[c4];
    int head = cl >> 3;
    #pragma unroll
    for (int rr = 0; rr < 4; rr++) {
        int grow = rowbase + g * 4 + rr;
        float4 a = acc[rr];
        if (grow < N_NODES) {
            __half2 lo = __floats2half2_rn(a.x, a.y);
            __half2 hi = __floats2half2_rn(a.z, a.w);
            uint2 pk;
            pk.x = *(unsigned int*)&lo;
            pk.y = *(unsigned int*)&hi;
            *(uint2*)&H16[(size_t)grow * 128 + c4] = pk;
        }
        float ps = a.x * as4.x + a.y * as4.y + a.z * as4.z + a.w * as4.w;
        float pd = a.x * ad4.x + a.y * ad4.y + a.z * ad4.z + a.w * ad4.w;
        ps += __shfl_xor(ps, 1); ps += __shfl_xor(ps, 2); ps += __shfl_xor(ps, 4);
        pd += __shfl_xor(pd, 1); pd += __shfl_xor(pd, 2); pd += __shfl_xor(pd, 4);
        if ((cl & 7) == 0 && grow < N_NODES) {
            a_s[grow * 4 + head] = ps;
            a_d[grow * 4 + head] = pd;
        }
    }
}

__global__ __launch_bounds__(256) void k_hist_gemm(
    const int* __restrict__ ei, int* __restrict__ histG,
    const float* __restrict__ X, const float* __restrict__ W,
    const float* __restrict__ attS, const float* __restrict__ attD,
    __half* __restrict__ H16, float* __restrict__ a_s, float* __restrict__ a_d) {
    __shared__ __align__(16) char smem[40960];
    int t = threadIdx.x;
    if (blockIdx.x < NWA) {
        int* h = (int*)smem;
        for (int i = t; i < NBKT; i += 256) h[i] = 0;
        __syncthreads();
        int base = blockIdx.x * EPW;
        #pragma unroll 4
        for (int j = 0; j < EPW / 256; j++) {
            int e = base + t + 256 * j;
            if (e < NE_TOT) {
                int d = (e < E_EDGES) ? ei[E_EDGES + e] : (e - E_EDGES);
                atomicAdd(&h[d >> BSH], 1);
            }
        }
        __syncthreads();
        for (int i = t; i < NBKT; i += 256) histG[blockIdx.x * NBKT + i] = h[i];
    } else {
        float* Wl = (float*)smem;              // 64*128 floats = 32KB
        float* xs = (float*)(smem + 32768);    // 32*64 floats = 8KB
        gemm_att_body(blockIdx.x - NWA, t, Wl, xs, X, W, attS, attD, H16, a_s, a_d);
    }
}

// standalone GEMM (layer 2)
__global__ __launch_bounds__(256) void k_gemm_att(
    const float* __restrict__ X, const float* __restrict__ W,
    const float* __restrict__ attS, const float* __restrict__ attD,
    __half* __restrict__ H16, float* __restrict__ a_s, float* __restrict__ a_d) {
    __shared__ float Wl[64 * 128];
    __shared__ float xs[32 * 64];
    gemm_att_body(blockIdx.x, threadIdx.x, Wl, xs, X, W, attS, attD, H16, a_s, a_d);
}

// ---------------- bucketed CSR build (rest) ----------------

__global__ __launch_bounds__(512) void k_bktscan(int* __restrict__ histG,
                                                 int* __restrict__ bktTotal) {
    __shared__ int sh[512];
    int b = blockIdx.x;            // bucket
    int t = threadIdx.x;           // workgroup index
    int v = (t < NWA) ? histG[t * NBKT + b] : 0;
    sh[t] = v;
    __syncthreads();
    for (int d = 1; d < 512; d <<= 1) {
        int x = (t >= d) ? sh[t - d] : 0;
        __syncthreads();
        sh[t] += x;
        __syncthreads();
    }
    if (t < NWA) histG[t * NBKT + b] = sh[t] - v;   // exclusive
    if (t == 511) bktTotal[b] = sh[511];
}

__global__ __launch_bounds__(512) void k_bktbase(const int* __restrict__ bktTotal,
                                                 int* __restrict__ bktBase,
                                                 int* __restrict__ row_start) {
    __shared__ int sc[512];
    int t = threadIdx.x;
    int v = (t < NBKT) ? bktTotal[t] : 0;
    sc[t] = v;
    __syncthreads();
    for (int d = 1; d < 512; d <<= 1) {
        int x = (t >= d) ? sc[t - d] : 0;
        __syncthreads();
        sc[t] += x;
        __syncthreads();
    }
    if (t < NBKT) bktBase[t] = sc[t] - v;
    if (t == NBKT - 1) { bktBase[NBKT] = sc[t]; row_start[N_NODES] = sc[t]; }
}

__global__ __launch_bounds__(256) void k_binscatter(const int* __restrict__ ei,
                                                    const int* __restrict__ histG,
                                                    const int* __restrict__ bktBase,
                                                    int2* __restrict__ pairs) {
    __shared__ int lofs[NBKT];
    int t = threadIdx.x;
    for (int i = t; i < NBKT; i += 256)
        lofs[i] = bktBase[i] + histG[blockIdx.x * NBKT + i];
    __syncthreads();
    int base = blockIdx.x * EPW;
    #pragma unroll 4
    for (int j = 0; j < EPW / 256; j++) {
        int e = base + t + 256 * j;
        if (e < NE_TOT) {
            int s, d;
            if (e < E_EDGES) { s = ei[e]; d = ei[E_EDGES + e]; }
            else             { s = d = e - E_EDGES; }
            int pos = atomicAdd(&lofs[d >> BSH], 1);
            pairs[pos] = make_int2(s, d);
        }
    }
}

__global__ __launch_bounds__(256) void k_bucketsort(const int2* __restrict__ pairs,
                                                    const int* __restrict__ bktBase,
                                                    int* __restrict__ row_start,
                                                    int* __restrict__ col) {
    __shared__ int cnt[1 << BSH];
    __shared__ int sc[1 << BSH];
    __shared__ int cur[1 << BSH];
    int b = blockIdx.x, t = threadIdx.x;
    int nbeg = b << BSH;
    int ebeg = bktBase[b], eend = bktBase[b + 1];
    if (t < (1 << BSH)) cnt[t] = 0;
    __syncthreads();
    for (int j = ebeg + t; j < eend; j += 256)
        atomicAdd(&cnt[pairs[j].y - nbeg], 1);
    __syncthreads();
    int v = (t < (1 << BSH)) ? cnt[t] : 0;
    if (t < (1 << BSH)) sc[t] = v;
    __syncthreads();
    for (int d = 1; d < (1 << BSH); d <<= 1) {
        int x = 0;
        if (t < (1 << BSH) && t >= d) x = sc[t - d];
        __syncthreads();
        if (t < (1 << BSH)) sc[t] += x;
        __syncthreads();
    }
    if (t < (1 << BSH)) {
        int pos = ebeg + sc[t] - v;      // exclusive
        cur[t] = pos;
        int node = nbeg + t;
        if (node < N_NODES) row_start[node] = pos;
    }
    __syncthreads();
    for (int j = ebeg + t; j < eend; j += 256) {
        int2 p = pairs[j];
        int pos = atomicAdd(&cur[p.y - nbeg], 1);
        col[pos] = p.x;
    }
}

// ---------------- Attention aggregation ----------------

__device__ inline float sel4(float4 v, int i) {
    float r = v.x;
    if (i == 1) r = v.y;
    if (i == 2) r = v.z;
    if (i == 3) r = v.w;
    return r;
}

__device__ inline float4 leaky4(float4 a, float4 b) {
    float4 e;
    e.x = a.x + b.x; e.x = e.x > 0.f ? e.x : 0.2f * e.x;
    e.y = a.y + b.y; e.y = e.y > 0.f ? e.y : 0.2f * e.y;
    e.z = a.z + b.z; e.z = e.z > 0.f ? e.z : 0.2f * e.z;
    e.w = a.w + b.w; e.w = e.w > 0.f ? e.w : 0.2f * e.w;
    return e;
}

#define ACC8(q, raw)                                              \
    do {                                                          \
        const __half2* hp_ = (const __half2*)&(raw);              \
        float2 f0_ = __half22float2(hp_[0]);                      \
        float2 f1_ = __half22float2(hp_[1]);                      \
        float2 f2_ = __half22float2(hp_[2]);                      \
        float2 f3_ = __half22float2(hp_[3]);                      \
        acc8[0] = fmaf((q), f0_.x, acc8[0]);                      \
        acc8[1] = fmaf((q), f0_.y, acc8[1]);                      \
        acc8[2] = fmaf((q), f1_.x, acc8[2]);                      \
        acc8[3] = fmaf((q), f1_.y, acc8[3]);                      \
        acc8[4] = fmaf((q), f2_.x, acc8[4]);                      \
        acc8[5] = fmaf((q), f2_.y, acc8[5]);                      \
        acc8[6] = fmaf((q), f3_.x, acc8[6]);                      \
        acc8[7] = fmaf((q), f3_.y, acc8[7]);                      \
    } while (0)

// consume geometry: 4 edge slots x 16 channel-lanes x 8 ch/lane,
// 4-edge explicit load batching for memory-level parallelism
template<int MODE>   // 1: layer-1 (ELU -> Hout fp32); 0: layer-2 (fused out-proj)
__global__ __launch_bounds__(256) void k_agg(
    const __half* __restrict__ H16, const float* __restrict__ a_s,
    const float* __restrict__ a_d, const int* __restrict__ row_start,
    const int* __restrict__ col, const float* __restrict__ bias,
    float* __restrict__ Hout,
    const float* __restrict__ Wout, const float* __restrict__ bout,
    float* __restrict__ out) {
    __shared__ float4 eS[4][CH];    // staged e -> p per wave
    __shared__ int    sS[4][CH];    // staged src per wave
    __shared__ float  WoT[(MODE == 0) ? 1024 : 1];  // transposed Wout [8][128]
    __shared__ float  boL[(MODE == 0) ? 8 : 1];

    if (MODE == 0) {
        for (int j = threadIdx.x; j < 1024; j += 256) {
            int o = j >> 7, k = j & 127;
            WoT[o * 128 + k] = Wout[k * 8 + o];
        }
        if (threadIdx.x < 8) boL[threadIdx.x] = bout[threadIdx.x];
        __syncthreads();
    }

    int wid = threadIdx.x >> 6;
    int lane = threadIdx.x & 63;
    int node = blockIdx.x * 4 + wid;
    if (node >= N_NODES) return;
    int beg = row_start[node], end = row_start[node + 1];
    int deg = end - beg;
    float4 ad4 = *(const float4*)&a_d[node * 4];
    float4* eA = eS[wid];
    int*    srcA = sS[wid];

    // pass 1: stage {src, e4} for first CH edges, track running max only
    float4 m = make_float4(-1e30f, -1e30f, -1e30f, -1e30f);
    for (int j = beg + lane; j < end; j += 64) {
        int src = col[j];
        float4 av = *(const float4*)&a_s[src * 4];
        float4 e = leaky4(av, ad4);
        int idx = j - beg;
        if (idx < CH) { srcA[idx] = src; eA[idx] = e; }
        m.x = fmaxf(m.x, e.x); m.y = fmaxf(m.y, e.y);
        m.z = fmaxf(m.z, e.z); m.w = fmaxf(m.w, e.w);
    }
    #pragma unroll
    for (int off = 32; off > 0; off >>= 1) {
        m.x = fmaxf(m.x, __shfl_xor(m.x, off));
        m.y = fmaxf(m.y, __shfl_xor(m.y, off));
        m.z = fmaxf(m.z, __shfl_xor(m.z, off));
        m.w = fmaxf(m.w, __shfl_xor(m.w, off));
    }

    // convert staged e -> p = exp(e-m), accumulate partial denom
    float4 s = make_float4(0.f, 0.f, 0.f, 0.f);
    int nst = min(deg, CH);
    for (int idx = lane; idx < nst; idx += 64) {
        float4 e = eA[idx];
        float4 p;
        p.x = __expf(e.x - m.x); p.y = __expf(e.y - m.y);
        p.z = __expf(e.z - m.z); p.w = __expf(e.w - m.w);
        s.x += p.x; s.y += p.y; s.z += p.z; s.w += p.w;
        eA[idx] = p;
    }
    // tail edges beyond CH (rare): recompute for denom
    for (int j = beg + CH + lane; j < end; j += 64) {
        int src = col[j];
        float4 av = *(const float4*)&a_s[src * 4];
        float4 e = leaky4(av, ad4);
        s.x += __expf(e.x - m.x); s.y += __expf(e.y - m.y);
        s.z += __expf(e.z - m.z); s.w += __expf(e.w - m.w);
    }
    #pragma unroll
    for (int off = 32; off > 0; off >>= 1) {
        s.x += __shfl_xor(s.x, off);
        s.y += __shfl_xor(s.y, off);
        s.z += __shfl_xor(s.z, off);
        s.w += __shfl_xor(s.w, off);
    }
    float4 inv;
    inv.x = 1.f / (s.x + 1e-16f);
    inv.y = 1.f / (s.y + 1e-16f);
    inv.z = 1.f / (s.z + 1e-16f);
    inv.w = 1.f / (s.w + 1e-16f);

    // consume: 4 edge slots x 16 channel-lanes (8 fp16 ch each = 16B load);
    // 4-edge batches per slot for MLP
    int eslot = lane >> 4, cl16 = lane & 15, head = cl16 >> 2;
    const __half* hbase = H16 + cl16 * 8;
    const float* pA = (const float*)eA;
    float acc8[8];
    #pragma unroll
    for (int k = 0; k < 8; k++) acc8[k] = 0.f;

    int i = eslot;
    for (; i + 12 < nst; i += 16) {
        int s0 = srcA[i];
        int s1 = srcA[i + 4];
        int s2 = srcA[i + 8];
        int s3 = srcA[i + 12];
        float q0 = pA[i * 4 + head];
        float q1 = pA[(i + 4) * 4 + head];
        float q2 = pA[(i + 8) * 4 + head];
        float q3 = pA[(i + 12) * 4 + head];
        float4 r0 = *(const float4*)(hbase + (size_t)s0 * 128);
        float4 r1 = *(const float4*)(hbase + (size_t)s1 * 128);
        float4 r2 = *(const float4*)(hbase + (size_t)s2 * 128);
        float4 r3 = *(const float4*)(hbase + (size_t)s3 * 128);
        ACC8(q0, r0);
        ACC8(q1, r1);
        ACC8(q2, r2);
        ACC8(q3, r3);
    }
    for (; i < nst; i += 4) {
        int src = srcA[i];
        float p = pA[i * 4 + head];
        float4 raw = *(const float4*)(hbase + (size_t)src * 128);
        ACC8(p, raw);
    }
    // overflow chunks (deg > CH, rare): restage then consume
    for (int cb = beg + CH; cb < end; cb += CH) {
        int cnt = min(end - cb, CH);
        for (int idx = lane; idx < cnt; idx += 64) {
            int src = col[cb + idx];
            float4 av = *(const float4*)&a_s[src * 4];
            float4 e = leaky4(av, ad4);
            float4 p;
            p.x = __expf(e.x - m.x); p.y = __expf(e.y - m.y);
            p.z = __expf(e.z - m.z); p.w = __expf(e.w - m.w);
            srcA[idx] = src; eA[idx] = p;
        }
        for (int ii = eslot; ii < cnt; ii += 4) {
            int src = srcA[ii];
            float p = pA[ii * 4 + head];
            float4 raw = *(const float4*)(hbase + (size_t)src * 128);
            ACC8(p, raw);
        }
    }

    #pragma unroll
    for (int k = 0; k < 8; k++) {
        acc8[k] += __shfl_xor(acc8[k], 16);
        acc8[k] += __shfl_xor(acc8[k], 32);
    }

    float ih = sel4(inv, head);
    if (MODE == 1) {
        if (eslot == 0) {
            const float* bp = &bias[cl16 * 8];
            float o[8];
            #pragma unroll
            for (int k = 0; k < 8; k++) {
                o[k] = acc8[k] * ih + bp[k];
                o[k] = o[k] > 0.f ? o[k] : expm1f(o[k]);
            }
            float* op = &Hout[(size_t)node * 128 + cl16 * 8];
            *(float4*)&op[0] = make_float4(o[0], o[1], o[2], o[3]);
            *(float4*)&op[4] = make_float4(o[4], o[5], o[6], o[7]);
        }
    } else {
        // fused output projection: h2 = acc*ih + b2 (all lanes hold it),
        // each eslot computes 2 of the 8 outputs
        const float* bp = &bias[cl16 * 8];
        float4 oa, ob;
        oa.x = acc8[0] * ih + bp[0]; oa.y = acc8[1] * ih + bp[1];
        oa.z = acc8[2] * ih + bp[2]; oa.w = acc8[3] * ih + bp[3];
        ob.x = acc8[4] * ih + bp[4]; ob.y = acc8[5] * ih + bp[5];
        ob.z = acc8[6] * ih + bp[6]; ob.w = acc8[7] * ih + bp[7];
        int o0 = eslot * 2;
        float p0 = 0.f, p1 = 0.f;
        {
            float4 wa = *(float4*)&WoT[o0 * 128 + cl16 * 8];
            float4 wb = *(float4*)&WoT[o0 * 128 + cl16 * 8 + 4];
            p0 = oa.x * wa.x + oa.y * wa.y + oa.z * wa.z + oa.w * wa.w
               + ob.x * wb.x + ob.y * wb.y + ob.z * wb.z + ob.w * wb.w;
            float4 wc = *(float4*)&WoT[(o0 + 1) * 128 + cl16 * 8];
            float4 wd = *(float4*)&WoT[(o0 + 1) * 128 + cl16 * 8 + 4];
            p1 = oa.x * wc.x + oa.y * wc.y + oa.z * wc.z + oa.w * wc.w
               + ob.x * wd.x + ob.y * wd.y + ob.z * wd.z + ob.w * wd.w;
        }
        #pragma unroll
        for (int d = 1; d <= 8; d <<= 1) {
            p0 += __shfl_xor(p0, d);
            p1 += __shfl_xor(p1, d);
        }
        if (cl16 == 0) {
            float2 ov = make_float2(p0 + boL[o0], p1 + boL[o0 + 1]);
            *(float2*)&out[(size_t)node * 8 + o0] = ov;
        }
    }
}

// ---------------- launch ----------------

extern "C" void kernel_launch(void* const* d_in, const int* in_sizes, int n_in,
                              void* d_out, int out_size, void* d_ws, size_t ws_size,
                              hipStream_t stream) {
    const float* x     = (const float*)d_in[0];
    const int*   ei    = (const int*)d_in[1];
    const float* W1    = (const float*)d_in[2];
    const float* attS1 = (const float*)d_in[3];
    const float* attD1 = (const float*)d_in[4];
    const float* b1    = (const float*)d_in[5];
    const float* W2    = (const float*)d_in[6];
    const float* attS2 = (const float*)d_in[7];
    const float* attD2 = (const float*)d_in[8];
    const float* b2    = (const float*)d_in[9];
    const float* Wout  = (const float*)d_in[10];
    const float* bout  = (const float*)d_in[11];
    float* out = (float*)d_out;

    char* ws = (char*)d_ws;
    size_t off = 0;
    auto alloc = [&](size_t bytes) -> void* {
        void* p = ws + off;
        off += (bytes + 255) & ~(size_t)255;
        return p;
    };
    float*  hB        = (float*)alloc((size_t)N_NODES * 128 * 4);
    __half* h16       = (__half*)alloc((size_t)N_NODES * 128 * 2);
    float*  a_s       = (float*)alloc((size_t)N_NODES * 4 * 4);
    float*  a_d       = (float*)alloc((size_t)N_NODES * 4 * 4);
    int*    row_start = (int*)alloc((size_t)(N_NODES + 1) * 4);
    int*    col       = (int*)alloc((size_t)NE_TOT * 4);
    int*    histG     = (int*)alloc((size_t)NWA * NBKT * 4);
    int*    bktTotal  = (int*)alloc((size_t)NBKT * 4);
    int*    bktBase   = (int*)alloc((size_t)(NBKT + 1) * 4);
    int2*   pairs     = (int2*)hB;   // alias: hB not live during CSR build

    int nbG = (N_NODES + 31) / 32;
    int nbA = (N_NODES + 3) / 4;

    // fused: binhist (blocks 0..NWA) || layer-1 GEMM (blocks NWA..NWA+nbG)
    k_hist_gemm<<<NWA + nbG, 256, 0, stream>>>(ei, histG, x, W1, attS1, attD1,
                                               h16, a_s, a_d);
    k_bktscan<<<NBKT, 512, 0, stream>>>(histG, bktTotal);
    k_bktbase<<<1, 512, 0, stream>>>(bktTotal, bktBase, row_start);
    k_binscatter<<<NWA, 256, 0, stream>>>(ei, histG, bktBase, pairs);
    k_bucketsort<<<NBKT, 256, 0, stream>>>(pairs, bktBase, row_start, col);

    k_agg<1><<<nbA, 256, 0, stream>>>(h16, a_s, a_d, row_start, col, b1, hB,
                                      Wout, bout, out);
    k_gemm_att<<<nbG, 256, 0, stream>>>(hB, W2, attS2, attD2, h16, a_s, a_d);
    k_agg<0><<<nbA, 256, 0, stream>>>(h16, a_s, a_d, row_start, col, b2, hB,
                                      Wout, bout, out);
}

// Round 10
// 257.185 us; speedup vs baseline: 1.2497x; 1.0440x over previous
//
#include <hip/hip_runtime.h>
#include <hip/hip_fp16.h>
#include <math.h>

#define N_NODES 50000
#define E_EDGES 1600000
#define NE_TOT  (E_EDGES + N_NODES)

// bucketed scatter geometry
#define BSH 7                                   // 128 nodes per bucket
#define NBKT ((N_NODES + 127) >> 7)             // 391 buckets
#define EPW 4096                                // edges per A-pass workgroup
#define NWA ((NE_TOT + EPW - 1) / EPW)          // 403 workgroups

#define CH 128                                  // staged edges per node chunk

// ---------------- fused: per-WG bucket histogram  ||  layer-1 GEMM ----------------

__device__ __forceinline__ void gemm_att_body(
    int bid, int t, float* Wl, float* xs,
    const float* __restrict__ X, const float* __restrict__ W,
    const float* __restrict__ attS, const float* __restrict__ attD,
    __half* __restrict__ H16, float* __restrict__ a_s, float* __restrict__ a_d) {
    int g = t >> 5, cl = t & 31, c4 = cl * 4;
    int rowbase = bid * 32;
    float4 acc[4];
    #pragma unroll
    for (int rr = 0; rr < 4; rr++) acc[rr] = make_float4(0.f, 0.f, 0.f, 0.f);

    for (int kp = 0; kp < 2; kp++) {
        __syncthreads();
        #pragma unroll
        for (int j = 0; j < 8; j++) {
            int f4 = t + 256 * j;
            int kk = f4 >> 5, cg = f4 & 31;
            *(float4*)&Wl[kk * 128 + cg * 4] =
                *(const float4*)&W[(kp * 64 + kk) * 128 + cg * 4];
        }
        #pragma unroll
        for (int j = 0; j < 2; j++) {
            int f4 = t + 256 * j;
            int r = f4 >> 4, k4 = f4 & 15;
            int grow = rowbase + r;
            float4 xv = make_float4(0.f, 0.f, 0.f, 0.f);
            if (grow < N_NODES) xv = *(const float4*)&X[grow * 128 + kp * 64 + k4 * 4];
            *(float4*)&xs[r * 64 + k4 * 4] = xv;
        }
        __syncthreads();
        #pragma unroll
        for (int k4 = 0; k4 < 16; k4++) {
            float4 xv[4];
            #pragma unroll
            for (int rr = 0; rr < 4; rr++)
                xv[rr] = *(float4*)&xs[(g * 4 + rr) * 64 + k4 * 4];
            #pragma unroll
            for (int kk = 0; kk < 4; kk++) {
                float4 wv = *(float4*)&Wl[(k4 * 4 + kk) * 128 + c4];
                #pragma unroll
                for (int rr = 0; rr < 4; rr++) {
                    float xc = (kk == 0) ? xv[rr].x : (kk == 1) ? xv[rr].y
                             : (kk == 2) ? xv[rr].z : xv[rr].w;
                    acc[rr].x += xc * wv.x;
                    acc[rr].y += xc * wv.y;
                    acc[rr].z += xc * wv.z;
                    acc[rr].w += xc * wv.w;
                }
            }
        }
    }

    float4 as4 = *(const float4*)&attS[c4];
    float4 ad4 = *(const float4*)&attD[c4];
    int head = cl >> 3;
    #pragma unroll
    for (int rr = 0; rr < 4; rr++) {
        int grow = rowbase + g * 4 + rr;
        float4 a = acc[rr];
        if (grow < N_NODES) {
            __half2 lo = __floats2half2_rn(a.x, a.y);
            __half2 hi = __floats2half2_rn(a.z, a.w);
            uint2 pk;
            pk.x = *(unsigned int*)&lo;
            pk.y = *(unsigned int*)&hi;
            *(uint2*)&H16[(size_t)grow * 128 + c4] = pk;
        }
        float ps = a.x * as4.x + a.y * as4.y + a.z * as4.z + a.w * as4.w;
        float pd = a.x * ad4.x + a.y * ad4.y + a.z * ad4.z + a.w * ad4.w;
        ps += __shfl_xor(ps, 1); ps += __shfl_xor(ps, 2); ps += __shfl_xor(ps, 4);
        pd += __shfl_xor(pd, 1); pd += __shfl_xor(pd, 2); pd += __shfl_xor(pd, 4);
        if ((cl & 7) == 0 && grow < N_NODES) {
            a_s[grow * 4 + head] = ps;
            a_d[grow * 4 + head] = pd;
        }
    }
}

__global__ __launch_bounds__(256) void k_hist_gemm(
    const int* __restrict__ ei, int* __restrict__ histG,
    const float* __restrict__ X, const float* __restrict__ W,
    const float* __restrict__ attS, const float* __restrict__ attD,
    __half* __restrict__ H16, float* __restrict__ a_s, float* __restrict__ a_d) {
    __shared__ __align__(16) char smem[40960];
    int t = threadIdx.x;
    if (blockIdx.x < NWA) {
        int* h = (int*)smem;
        for (int i = t; i < NBKT; i += 256) h[i] = 0;
        __syncthreads();
        int base = blockIdx.x * EPW;
        #pragma unroll 4
        for (int j = 0; j < EPW / 256; j++) {
            int e = base + t + 256 * j;
            if (e < NE_TOT) {
                int d = (e < E_EDGES) ? ei[E_EDGES + e] : (e - E_EDGES);
                atomicAdd(&h[d >> BSH], 1);
            }
        }
        __syncthreads();
        for (int i = t; i < NBKT; i += 256) histG[blockIdx.x * NBKT + i] = h[i];
    } else {
        float* Wl = (float*)smem;              // 64*128 floats = 32KB
        float* xs = (float*)(smem + 32768);    // 32*64 floats = 8KB
        gemm_att_body(blockIdx.x - NWA, t, Wl, xs, X, W, attS, attD, H16, a_s, a_d);
    }
}

// standalone GEMM (layer 2)
__global__ __launch_bounds__(256) void k_gemm_att(
    const float* __restrict__ X, const float* __restrict__ W,
    const float* __restrict__ attS, const float* __restrict__ attD,
    __half* __restrict__ H16, float* __restrict__ a_s, float* __restrict__ a_d) {
    __shared__ float Wl[64 * 128];
    __shared__ float xs[32 * 64];
    gemm_att_body(blockIdx.x, threadIdx.x, Wl, xs, X, W, attS, attD, H16, a_s, a_d);
}

// ---------------- bucketed CSR build (rest) ----------------

__global__ __launch_bounds__(512) void k_bktscan(int* __restrict__ histG,
                                                 int* __restrict__ bktTotal) {
    __shared__ int sh[512];
    int b = blockIdx.x;            // bucket
    int t = threadIdx.x;           // workgroup index
    int v = (t < NWA) ? histG[t * NBKT + b] : 0;
    sh[t] = v;
    __syncthreads();
    for (int d = 1; d < 512; d <<= 1) {
        int x = (t >= d) ? sh[t - d] : 0;
        __syncthreads();
        sh[t] += x;
        __syncthreads();
    }
    if (t < NWA) histG[t * NBKT + b] = sh[t] - v;   // exclusive
    if (t == 511) bktTotal[b] = sh[511];
}

__global__ __launch_bounds__(512) void k_bktbase(const int* __restrict__ bktTotal,
                                                 int* __restrict__ bktBase,
                                                 int* __restrict__ row_start) {
    __shared__ int sc[512];
    int t = threadIdx.x;
    int v = (t < NBKT) ? bktTotal[t] : 0;
    sc[t] = v;
    __syncthreads();
    for (int d = 1; d < 512; d <<= 1) {
        int x = (t >= d) ? sc[t - d] : 0;
        __syncthreads();
        sc[t] += x;
        __syncthreads();
    }
    if (t < NBKT) bktBase[t] = sc[t] - v;
    if (t == NBKT - 1) { bktBase[NBKT] = sc[t]; row_start[N_NODES] = sc[t]; }
}

__global__ __launch_bounds__(256) void k_binscatter(const int* __restrict__ ei,
                                                    const int* __restrict__ histG,
                                                    const int* __restrict__ bktBase,
                                                    int2* __restrict__ pairs) {
    __shared__ int lofs[NBKT];
    int t = threadIdx.x;
    for (int i = t; i < NBKT; i += 256)
        lofs[i] = bktBase[i] + histG[blockIdx.x * NBKT + i];
    __syncthreads();
    int base = blockIdx.x * EPW;
    #pragma unroll 4
    for (int j = 0; j < EPW / 256; j++) {
        int e = base + t + 256 * j;
        if (e < NE_TOT) {
            int s, d;
            if (e < E_EDGES) { s = ei[e]; d = ei[E_EDGES + e]; }
            else             { s = d = e - E_EDGES; }
            int pos = atomicAdd(&lofs[d >> BSH], 1);
            pairs[pos] = make_int2(s, d);
        }
    }
}

__global__ __launch_bounds__(256) void k_bucketsort(const int2* __restrict__ pairs,
                                                    const int* __restrict__ bktBase,
                                                    int* __restrict__ row_start,
                                                    int* __restrict__ col) {
    __shared__ int cnt[1 << BSH];
    __shared__ int sc[1 << BSH];
    __shared__ int cur[1 << BSH];
    int b = blockIdx.x, t = threadIdx.x;
    int nbeg = b << BSH;
    int ebeg = bktBase[b], eend = bktBase[b + 1];
    if (t < (1 << BSH)) cnt[t] = 0;
    __syncthreads();
    for (int j = ebeg + t; j < eend; j += 256)
        atomicAdd(&cnt[pairs[j].y - nbeg], 1);
    __syncthreads();
    int v = (t < (1 << BSH)) ? cnt[t] : 0;
    if (t < (1 << BSH)) sc[t] = v;
    __syncthreads();
    for (int d = 1; d < (1 << BSH); d <<= 1) {
        int x = 0;
        if (t < (1 << BSH) && t >= d) x = sc[t - d];
        __syncthreads();
        if (t < (1 << BSH)) sc[t] += x;
        __syncthreads();
    }
    if (t < (1 << BSH)) {
        int pos = ebeg + sc[t] - v;      // exclusive
        cur[t] = pos;
        int node = nbeg + t;
        if (node < N_NODES) row_start[node] = pos;
    }
    __syncthreads();
    for (int j = ebeg + t; j < eend; j += 256) {
        int2 p = pairs[j];
        int pos = atomicAdd(&cur[p.y - nbeg], 1);
        col[pos] = p.x;
    }
}

// ---------------- Attention aggregation ----------------

__device__ inline float sel4(float4 v, int i) {
    float r = v.x;
    if (i == 1) r = v.y;
    if (i == 2) r = v.z;
    if (i == 3) r = v.w;
    return r;
}

// p = exp(leaky_relu(a + b)) — no max subtraction (|logits| <~ 2, fp32-safe;
// alpha = p/sum(p) is mathematically identical to the max-shifted form)
__device__ inline float4 expleaky4(float4 a, float4 b) {
    float4 e, p;
    e.x = a.x + b.x; e.x = e.x > 0.f ? e.x : 0.2f * e.x; p.x = __expf(e.x);
    e.y = a.y + b.y; e.y = e.y > 0.f ? e.y : 0.2f * e.y; p.y = __expf(e.y);
    e.z = a.z + b.z; e.z = e.z > 0.f ? e.z : 0.2f * e.z; p.z = __expf(e.z);
    e.w = a.w + b.w; e.w = e.w > 0.f ? e.w : 0.2f * e.w; p.w = __expf(e.w);
    return p;
}

#define ACC8(q, raw)                                              \
    do {                                                          \
        const __half2* hp_ = (const __half2*)&(raw);              \
        float2 f0_ = __half22float2(hp_[0]);                      \
        float2 f1_ = __half22float2(hp_[1]);                      \
        float2 f2_ = __half22float2(hp_[2]);                      \
        float2 f3_ = __half22float2(hp_[3]);                      \
        acc8[0] = fmaf((q), f0_.x, acc8[0]);                      \
        acc8[1] = fmaf((q), f0_.y, acc8[1]);                      \
        acc8[2] = fmaf((q), f1_.x, acc8[2]);                      \
        acc8[3] = fmaf((q), f1_.y, acc8[3]);                      \
        acc8[4] = fmaf((q), f2_.x, acc8[4]);                      \
        acc8[5] = fmaf((q), f2_.y, acc8[5]);                      \
        acc8[6] = fmaf((q), f3_.x, acc8[6]);                      \
        acc8[7] = fmaf((q), f3_.y, acc8[7]);                      \
    } while (0)

// consume geometry: 4 edge slots x 16 channel-lanes x 8 ch/lane
template<int MODE>   // 1: layer-1 (ELU -> Hout fp32); 0: layer-2 (fused out-proj)
__global__ __launch_bounds__(256) void k_agg(
    const __half* __restrict__ H16, const float* __restrict__ a_s,
    const float* __restrict__ a_d, const int* __restrict__ row_start,
    const int* __restrict__ col, const float* __restrict__ bias,
    float* __restrict__ Hout,
    const float* __restrict__ Wout, const float* __restrict__ bout,
    float* __restrict__ out) {
    __shared__ float4 eS[4][CH];    // staged p per wave
    __shared__ int    sS[4][CH];    // staged src per wave
    __shared__ float  WoT[(MODE == 0) ? 1024 : 1];  // transposed Wout [8][128]
    __shared__ float  boL[(MODE == 0) ? 8 : 1];

    if (MODE == 0) {
        for (int j = threadIdx.x; j < 1024; j += 256) {
            int o = j >> 7, k = j & 127;
            WoT[o * 128 + k] = Wout[k * 8 + o];
        }
        if (threadIdx.x < 8) boL[threadIdx.x] = bout[threadIdx.x];
        __syncthreads();
    }

    int wid = threadIdx.x >> 6;
    int lane = threadIdx.x & 63;
    int node = blockIdx.x * 4 + wid;
    if (node >= N_NODES) return;
    int beg = row_start[node], end = row_start[node + 1];
    int deg = end - beg;
    float4 ad4 = *(const float4*)&a_d[node * 4];
    float4* eA = eS[wid];
    int*    srcA = sS[wid];

    // single pass: p = exp(leaky(e)), stage {src,p} (first CH), accumulate denom
    float4 s = make_float4(0.f, 0.f, 0.f, 0.f);
    for (int j = beg + lane; j < end; j += 64) {
        int src = col[j];
        float4 av = *(const float4*)&a_s[src * 4];
        float4 p = expleaky4(av, ad4);
        int idx = j - beg;
        if (idx < CH) { srcA[idx] = src; eA[idx] = p; }
        s.x += p.x; s.y += p.y; s.z += p.z; s.w += p.w;
    }
    #pragma unroll
    for (int off = 32; off > 0; off >>= 1) {
        s.x += __shfl_xor(s.x, off);
        s.y += __shfl_xor(s.y, off);
        s.z += __shfl_xor(s.z, off);
        s.w += __shfl_xor(s.w, off);
    }
    float4 inv;
    inv.x = 1.f / (s.x + 1e-16f);
    inv.y = 1.f / (s.y + 1e-16f);
    inv.z = 1.f / (s.z + 1e-16f);
    inv.w = 1.f / (s.w + 1e-16f);

    // consume: 4 edge slots x 16 channel-lanes (8 fp16 ch each = 16B load);
    // 4-edge batches per slot for MLP
    int eslot = lane >> 4, cl16 = lane & 15, head = cl16 >> 2;
    const __half* hbase = H16 + cl16 * 8;
    const float* pA = (const float*)eA;
    float acc8[8];
    #pragma unroll
    for (int k = 0; k < 8; k++) acc8[k] = 0.f;

    int nst = min(deg, CH);
    int i = eslot;
    for (; i + 12 < nst; i += 16) {
        int s0 = srcA[i];
        int s1 = srcA[i + 4];
        int s2 = srcA[i + 8];
        int s3 = srcA[i + 12];
        float q0 = pA[i * 4 + head];
        float q1 = pA[(i + 4) * 4 + head];
        float q2 = pA[(i + 8) * 4 + head];
        float q3 = pA[(i + 12) * 4 + head];
        float4 r0 = *(const float4*)(hbase + (size_t)s0 * 128);
        float4 r1 = *(const float4*)(hbase + (size_t)s1 * 128);
        float4 r2 = *(const float4*)(hbase + (size_t)s2 * 128);
        float4 r3 = *(const float4*)(hbase + (size_t)s3 * 128);
        ACC8(q0, r0);
        ACC8(q1, r1);
        ACC8(q2, r2);
        ACC8(q3, r3);
    }
    for (; i < nst; i += 4) {
        int src = srcA[i];
        float p = pA[i * 4 + head];
        float4 raw = *(const float4*)(hbase + (size_t)src * 128);
        ACC8(p, raw);
    }
    // overflow chunks (deg > CH, rare): restage then consume
    for (int cb = beg + CH; cb < end; cb += CH) {
        int cnt = min(end - cb, CH);
        for (int idx = lane; idx < cnt; idx += 64) {
            int src = col[cb + idx];
            float4 av = *(const float4*)&a_s[src * 4];
            float4 p = expleaky4(av, ad4);
            srcA[idx] = src; eA[idx] = p;
        }
        for (int ii = eslot; ii < cnt; ii += 4) {
            int src = srcA[ii];
            float p = pA[ii * 4 + head];
            float4 raw = *(const float4*)(hbase + (size_t)src * 128);
            ACC8(p, raw);
        }
    }

    #pragma unroll
    for (int k = 0; k < 8; k++) {
        acc8[k] += __shfl_xor(acc8[k], 16);
        acc8[k] += __shfl_xor(acc8[k], 32);
    }

    float ih = sel4(inv, head);
    if (MODE == 1) {
        if (eslot == 0) {
            const float* bp = &bias[cl16 * 8];
            float o[8];
            #pragma unroll
            for (int k = 0; k < 8; k++) {
                o[k] = acc8[k] * ih + bp[k];
                o[k] = o[k] > 0.f ? o[k] : expm1f(o[k]);
            }
            float* op = &Hout[(size_t)node * 128 + cl16 * 8];
            *(float4*)&op[0] = make_float4(o[0], o[1], o[2], o[3]);
            *(float4*)&op[4] = make_float4(o[4], o[5], o[6], o[7]);
        }
    } else {
        // fused output projection
        const float* bp = &bias[cl16 * 8];
        float4 oa, ob;
        oa.x = acc8[0] * ih + bp[0]; oa.y = acc8[1] * ih + bp[1];
        oa.z = acc8[2] * ih + bp[2]; oa.w = acc8[3] * ih + bp[3];
        ob.x = acc8[4] * ih + bp[4]; ob.y = acc8[5] * ih + bp[5];
        ob.z = acc8[6] * ih + bp[6]; ob.w = acc8[7] * ih + bp[7];
        int o0 = eslot * 2;
        float p0 = 0.f, p1 = 0.f;
        {
            float4 wa = *(float4*)&WoT[o0 * 128 + cl16 * 8];
            float4 wb = *(float4*)&WoT[o0 * 128 + cl16 * 8 + 4];
            p0 = oa.x * wa.x + oa.y * wa.y + oa.z * wa.z + oa.w * wa.w
               + ob.x * wb.x + ob.y * wb.y + ob.z * wb.z + ob.w * wb.w;
            float4 wc = *(float4*)&WoT[(o0 + 1) * 128 + cl16 * 8];
            float4 wd = *(float4*)&WoT[(o0 + 1) * 128 + cl16 * 8 + 4];
            p1 = oa.x * wc.x + oa.y * wc.y + oa.z * wc.z + oa.w * wc.w
               + ob.x * wd.x + ob.y * wd.y + ob.z * wd.z + ob.w * wd.w;
        }
        #pragma unroll
        for (int d = 1; d <= 8; d <<= 1) {
            p0 += __shfl_xor(p0, d);
            p1 += __shfl_xor(p1, d);
        }
        if (cl16 == 0) {
            float2 ov = make_float2(p0 + boL[o0], p1 + boL[o0 + 1]);
            *(float2*)&out[(size_t)node * 8 + o0] = ov;
        }
    }
}

// ---------------- launch ----------------

extern "C" void kernel_launch(void* const* d_in, const int* in_sizes, int n_in,
                              void* d_out, int out_size, void* d_ws, size_t ws_size,
                              hipStream_t stream) {
    const float* x     = (const float*)d_in[0];
    const int*   ei    = (const int*)d_in[1];
    const float* W1    = (const float*)d_in[2];
    const float* attS1 = (const float*)d_in[3];
    const float* attD1 = (const float*)d_in[4];
    const float* b1    = (const float*)d_in[5];
    const float* W2    = (const float*)d_in[6];
    const float* attS2 = (const float*)d_in[7];
    const float* attD2 = (const float*)d_in[8];
    const float* b2    = (const float*)d_in[9];
    const float* Wout  = (const float*)d_in[10];
    const float* bout  = (const float*)d_in[11];
    float* out = (float*)d_out;

    char* ws = (char*)d_ws;
    size_t off = 0;
    auto alloc = [&](size_t bytes) -> void* {
        void* p = ws + off;
        off += (bytes + 255) & ~(size_t)255;
        return p;
    };
    float*  hB        = (float*)alloc((size_t)N_NODES * 128 * 4);
    __half* h16       = (__half*)alloc((size_t)N_NODES * 128 * 2);
    float*  a_s       = (float*)alloc((size_t)N_NODES * 4 * 4);
    float*  a_d       = (float*)alloc((size_t)N_NODES * 4 * 4);
    int*    row_start = (int*)alloc((size_t)(N_NODES + 1) * 4);
    int*    col       = (int*)alloc((size_t)NE_TOT * 4);
    int*    histG     = (int*)alloc((size_t)NWA * NBKT * 4);
    int*    bktTotal  = (int*)alloc((size_t)NBKT * 4);
    int*    bktBase   = (int*)alloc((size_t)(NBKT + 1) * 4);
    int2*   pairs     = (int2*)hB;   // alias: hB not live during CSR build

    int nbG = (N_NODES + 31) / 32;
    int nbA = (N_NODES + 3) / 4;

    // fused: binhist (blocks 0..NWA) || layer-1 GEMM (blocks NWA..NWA+nbG)
    k_hist_gemm<<<NWA + nbG, 256, 0, stream>>>(ei, histG, x, W1, attS1, attD1,
                                               h16, a_s, a_d);
    k_bktscan<<<NBKT, 512, 0, stream>>>(histG, bktTotal);
    k_bktbase<<<1, 512, 0, stream>>>(bktTotal, bktBase, row_start);
    k_binscatter<<<NWA, 256, 0, stream>>>(ei, histG, bktBase, pairs);
    k_bucketsort<<<NBKT, 256, 0, stream>>>(pairs, bktBase, row_start, col);

    k_agg<1><<<nbA, 256, 0, stream>>>(h16, a_s, a_d, row_start, col, b1, hB,
                                      Wout, bout, out);
    k_gemm_att<<<nbG, 256, 0, stream>>>(hB, W2, attS2, attD2, h16, a_s, a_d);
    k_agg<0><<<nbA, 256, 0, stream>>>(h16, a_s, a_d, row_start, col, b2, hB,
                                      Wout, bout, out);
}